// Round 5
// baseline (248.525 us; speedup 1.0000x reference)
//
#include <hip/hip_runtime.h>
#include <math.h>

#define NBLOCKS 3840
#define NTHREADS 256
#define THREADS_TOTAL (NBLOCKS * NTHREADS)   // 983,040
#define ITERS 5                               // 983,040 * 5 = 4,915,200 quads

// image geometry (fixed by the reference): W=640, H=480
#define ROW4 160
#define IMG4 76800

// constants from the reference
#define K_CX 313.0447587080473f
#define K_CY 238.44389626620386f
#define K_RFX (1.0f / 582.6244816773795f)
#define K_RFY (1.0f / 582.6910327098864f)
#define LN2_SQ 0.48045301391820142467f   // (ln 2)^2

// acc layout (doubles): [0]=n, [1]=sumX, [2]=sumY, [3]=sumZ, [4]=sumLog
// ---------------------------------------------------------------------------
// per-quad compute (col/row known): masked d^2*a^2, d^2*b^2, d^2, dlog^2, count
__device__ __forceinline__ void quad_accum(const float4& f, const float4& r,
                                           int col4, float b,
                                           float& sx, float& sy, float& sz,
                                           float& sl2, float& cnt) {
    float fv[4] = {f.x, f.y, f.z, f.w};
    float rv[4] = {r.x, r.y, r.z, r.w};
#pragma unroll
    for (int j = 0; j < 4; ++j) {
        float fj = fv[j], rj = rv[j];
        bool m = (rj > 0.f) & (rj < 1.f) & (fj > 0.f) & (fj < 1.f);
        // Inside the mask r,f in (0,1) and a,b != 0 (CX/CY non-integer) -> the
        // reference's ==0->eps replacements are no-ops; x/y diffs factor to d*a, d*b.
        float a  = ((float)(col4 + j) - K_CX) * K_RFX;
        float d  = rj - fj;
        float dl = __log2f(rj) - __log2f(fj);
        d  = m ? d  : 0.f;
        dl = m ? dl : 0.f;
        float da = d * a, db = d * b;
        sx  += da * da;
        sy  += db * db;
        sz  += d * d;
        sl2 += dl * dl;
        cnt += m ? 1.f : 0.f;
    }
}

// wave + block reduce, then 5 device-scope f64 atomic adds (HW global_atomic_add_f64)
__device__ __forceinline__ void block_reduce_atomic(
        float cnt, float sx, float sy, float sz, float sl,
        double* __restrict__ acc) {
#pragma unroll
    for (int o = 32; o > 0; o >>= 1) {
        cnt += __shfl_down(cnt, o);
        sx  += __shfl_down(sx, o);
        sy  += __shfl_down(sy, o);
        sz  += __shfl_down(sz, o);
        sl  += __shfl_down(sl, o);
    }
    __shared__ float part[4][5];
    int wave = threadIdx.x >> 6;
    int lane = threadIdx.x & 63;
    if (lane == 0) {
        part[wave][0] = cnt; part[wave][1] = sx; part[wave][2] = sy;
        part[wave][3] = sz;  part[wave][4] = sl;
    }
    __syncthreads();
    if (threadIdx.x == 0) {
        double t[5] = {0, 0, 0, 0, 0};
#pragma unroll
        for (int w = 0; w < 4; ++w)
#pragma unroll
            for (int j = 0; j < 5; ++j) t[j] += (double)part[w][j];
#pragma unroll
        for (int j = 0; j < 5; ++j) unsafeAtomicAdd(&acc[j], t[j]);
    }
}

// ---------------------------------------------------------------------------
// fast path: exactly ITERS strided quads per thread; all 10 loads pinned up front
__global__ __launch_bounds__(NTHREADS) void ddd_reduce5_kernel(
        const float4* __restrict__ fake, const float4* __restrict__ real,
        double* __restrict__ acc) {
    const int tid = blockIdx.x * NTHREADS + threadIdx.x;

    // issue all loads back-to-back, interleaved so consumption order == issue order
    float4 fb[ITERS], rb[ITERS];
#pragma unroll
    for (int k = 0; k < ITERS; ++k) {
        fb[k] = fake[tid + k * THREADS_TOTAL];
        rb[k] = real[tid + k * THREADS_TOTAL];
    }
    // hard fence: nothing from below may be hoisted between/above the loads
    __builtin_amdgcn_sched_barrier(0);

    float cnt = 0.f, sx = 0.f, sy = 0.f, sz = 0.f, sl2 = 0.f;
#pragma unroll
    for (int k = 0; k < ITERS; ++k) {
        int idx  = tid + k * THREADS_TOTAL;
        int pos  = idx % IMG4;               // constant-divisor -> magic mul
        int col4 = (pos % ROW4) * 4;
        int h    = pos / ROW4;
        float b  = ((float)h - K_CY) * K_RFY;
        quad_accum(fb[k], rb[k], col4, b, sx, sy, sz, sl2, cnt);
    }

    block_reduce_atomic(cnt, sx, sy, sz, sl2 * LN2_SQ, acc);
}

// generic fallback: any total4 (grid-stride)
__global__ __launch_bounds__(NTHREADS) void ddd_reduce_gen_kernel(
        const float4* __restrict__ fake, const float4* __restrict__ real,
        double* __restrict__ acc, int total4) {
    float cnt = 0.f, sx = 0.f, sy = 0.f, sz = 0.f, sl2 = 0.f;
    for (int i = blockIdx.x * NTHREADS + threadIdx.x; i < total4; i += THREADS_TOTAL) {
        float4 f = fake[i];
        float4 r = real[i];
        int pos  = i % IMG4;
        int col4 = (pos % ROW4) * 4;
        int h    = pos / ROW4;
        float b  = ((float)h - K_CY) * K_RFY;
        quad_accum(f, r, col4, b, sx, sy, sz, sl2, cnt);
    }
    block_reduce_atomic(cnt, sx, sy, sz, sl2 * LN2_SQ, acc);
}

// ---------------------------------------------------------------------------
// trivial finalize: 5 coherent doubles -> loss (kernel boundary makes acc visible)
__global__ void finalize_kernel(const double* __restrict__ acc, float* __restrict__ out) {
    if (threadIdx.x == 0) {
        double n  = acc[0];
        double lx = sqrt(acc[1] / n);
        double ly = sqrt(acc[2] / n);
        double lz = sqrt(acc[3] / n);
        double ll = sqrt(acc[4] / n);
        double loss = 10.0 * (ll + fabs(10.0 * (3.0 - exp(lx) - exp(ly) - exp(lz))));
        out[0] = (float)loss;
    }
}

// ---------------------------------------------------------------------------
extern "C" void kernel_launch(void* const* d_in, const int* in_sizes, int n_in,
                              void* d_out, int out_size, void* d_ws, size_t ws_size,
                              hipStream_t stream) {
    const float4* fake = (const float4*)d_in[0];
    const float4* real = (const float4*)d_in[1];
    float* out = (float*)d_out;
    double* acc = (double*)d_ws;   // 40 bytes used

    int total  = in_sizes[0];
    int total4 = total / 4;

    hipMemsetAsync(acc, 0, 5 * sizeof(double), stream);  // graph-capturable memset node
    if (total4 == ITERS * THREADS_TOTAL) {
        ddd_reduce5_kernel<<<NBLOCKS, NTHREADS, 0, stream>>>(fake, real, acc);
    } else {
        ddd_reduce_gen_kernel<<<NBLOCKS, NTHREADS, 0, stream>>>(fake, real, acc, total4);
    }
    finalize_kernel<<<1, 64, 0, stream>>>(acc, out);
}

// Round 6
// 37.238 us; speedup vs baseline: 6.6739x; 6.6739x over previous
//
#include <hip/hip_runtime.h>
#include <math.h>

#define NBLOCKS 3840
#define NTHREADS 256
#define THREADS_TOTAL (NBLOCKS * NTHREADS)   // 983,040
#define ITERS 5                               // 983,040 * 5 = 4,915,200 quads

// image geometry (fixed by the reference): W=640, H=480
#define ROW4 160
#define IMG4 76800

// constants from the reference
#define K_CX 313.0447587080473f
#define K_CY 238.44389626620386f
#define K_RFX (1.0f / 582.6244816773795f)
#define K_RFY (1.0f / 582.6910327098864f)
#define LN2_SQ 0.48045301391820142467f   // (ln 2)^2

// ---------------------------------------------------------------------------
// per-quad compute (col/row known): masked d^2*a^2, d^2*b^2, d^2, dlog^2, count
__device__ __forceinline__ void quad_accum(const float4& f, const float4& r,
                                           int col4, float b,
                                           float& sx, float& sy, float& sz,
                                           float& sl2, float& cnt) {
    float fv[4] = {f.x, f.y, f.z, f.w};
    float rv[4] = {r.x, r.y, r.z, r.w};
#pragma unroll
    for (int j = 0; j < 4; ++j) {
        float fj = fv[j], rj = rv[j];
        bool m = (rj > 0.f) & (rj < 1.f) & (fj > 0.f) & (fj < 1.f);
        // Inside the mask r,f in (0,1) and a,b != 0 (CX/CY non-integer) -> the
        // reference's ==0->eps replacements are no-ops; x/y diffs factor to d*a, d*b.
        float a  = ((float)(col4 + j) - K_CX) * K_RFX;
        float d  = rj - fj;
        float dl = __log2f(rj) - __log2f(fj);
        d  = m ? d  : 0.f;
        dl = m ? dl : 0.f;
        float da = d * a, db = d * b;
        sx  += da * da;
        sy  += db * db;
        sz  += d * d;
        sl2 += dl * dl;
        cnt += m ? 1.f : 0.f;
    }
}

// wave + block reduce, then store 5 partials for this block (SoA, no atomics)
__device__ __forceinline__ void block_reduce_store(
        float cnt, float sx, float sy, float sz, float sl,
        double* __restrict__ partial, int nb, int bid) {
#pragma unroll
    for (int o = 32; o > 0; o >>= 1) {
        cnt += __shfl_down(cnt, o);
        sx  += __shfl_down(sx, o);
        sy  += __shfl_down(sy, o);
        sz  += __shfl_down(sz, o);
        sl  += __shfl_down(sl, o);
    }
    __shared__ float part[4][5];
    int wave = threadIdx.x >> 6;
    int lane = threadIdx.x & 63;
    if (lane == 0) {
        part[wave][0] = cnt; part[wave][1] = sx; part[wave][2] = sy;
        part[wave][3] = sz;  part[wave][4] = sl;
    }
    __syncthreads();
    if (threadIdx.x == 0) {
        double t[5] = {0, 0, 0, 0, 0};
#pragma unroll
        for (int w = 0; w < 4; ++w)
#pragma unroll
            for (int j = 0; j < 5; ++j) t[j] += (double)part[w][j];
#pragma unroll
        for (int j = 0; j < 5; ++j) partial[j * nb + bid] = t[j];
    }
}

// ---------------------------------------------------------------------------
// fast path: exactly ITERS strided quads per thread.
// __launch_bounds__(256, 4): allow up to 128 VGPR so the compiler can keep all
// 10 loads in flight (R4's default heuristic capped at 32 VGPR -> ~4-deep MLP).
// NO sched_barrier: R5 proved order-pinning + tight registers = serialized loads.
__global__ __launch_bounds__(NTHREADS, 4) void ddd_reduce5_kernel(
        const float4* __restrict__ fake, const float4* __restrict__ real,
        double* __restrict__ partial) {
    const int tid = blockIdx.x * NTHREADS + threadIdx.x;

    // issue all loads back-to-back, interleaved so consumption order == issue order
    float4 fb[ITERS], rb[ITERS];
#pragma unroll
    for (int k = 0; k < ITERS; ++k) {
        fb[k] = fake[tid + k * THREADS_TOTAL];
        rb[k] = real[tid + k * THREADS_TOTAL];
    }

    float cnt = 0.f, sx = 0.f, sy = 0.f, sz = 0.f, sl2 = 0.f;
#pragma unroll
    for (int k = 0; k < ITERS; ++k) {
        int idx  = tid + k * THREADS_TOTAL;
        int pos  = idx % IMG4;               // constant-divisor -> magic mul
        int col4 = (pos % ROW4) * 4;
        int h    = pos / ROW4;
        float b  = ((float)h - K_CY) * K_RFY;
        quad_accum(fb[k], rb[k], col4, b, sx, sy, sz, sl2, cnt);
    }

    block_reduce_store(cnt, sx, sy, sz, sl2 * LN2_SQ, partial, NBLOCKS, blockIdx.x);
}

// generic fallback: any total4 (grid-stride)
__global__ __launch_bounds__(NTHREADS) void ddd_reduce_gen_kernel(
        const float4* __restrict__ fake, const float4* __restrict__ real,
        double* __restrict__ partial, int total4) {
    float cnt = 0.f, sx = 0.f, sy = 0.f, sz = 0.f, sl2 = 0.f;
    for (int i = blockIdx.x * NTHREADS + threadIdx.x; i < total4; i += THREADS_TOTAL) {
        float4 f = fake[i];
        float4 r = real[i];
        int pos  = i % IMG4;
        int col4 = (pos % ROW4) * 4;
        int h    = pos / ROW4;
        float b  = ((float)h - K_CY) * K_RFY;
        quad_accum(f, r, col4, b, sx, sy, sz, sl2, cnt);
    }
    block_reduce_store(cnt, sx, sy, sz, sl2 * LN2_SQ, partial, NBLOCKS, blockIdx.x);
}

// ---------------------------------------------------------------------------
// finalize: 1024 threads sum nb partials per quantity, thread 0 computes loss
__global__ __launch_bounds__(1024) void finalize_kernel(
        const double* __restrict__ partial, int nb, float* __restrict__ out) {
    double t[5] = {0, 0, 0, 0, 0};
    for (int i = threadIdx.x; i < nb; i += 1024)
#pragma unroll
        for (int j = 0; j < 5; ++j) t[j] += partial[j * nb + i];
#pragma unroll
    for (int o = 32; o > 0; o >>= 1)
#pragma unroll
        for (int j = 0; j < 5; ++j) t[j] += __shfl_down(t[j], o);

    __shared__ double part[16][5];
    int wave = threadIdx.x >> 6;
    int lane = threadIdx.x & 63;
    if (lane == 0)
#pragma unroll
        for (int j = 0; j < 5; ++j) part[wave][j] = t[j];
    __syncthreads();

    if (threadIdx.x == 0) {
#pragma unroll
        for (int w = 1; w < 16; ++w)
#pragma unroll
            for (int j = 0; j < 5; ++j) part[0][j] += part[w][j];
        double n  = part[0][0];
        double lx = sqrt(part[0][1] / n);
        double ly = sqrt(part[0][2] / n);
        double lz = sqrt(part[0][3] / n);
        double ll = sqrt(part[0][4] / n);
        double loss = 10.0 * (ll + fabs(10.0 * (3.0 - exp(lx) - exp(ly) - exp(lz))));
        out[0] = (float)loss;
    }
}

// ---------------------------------------------------------------------------
extern "C" void kernel_launch(void* const* d_in, const int* in_sizes, int n_in,
                              void* d_out, int out_size, void* d_ws, size_t ws_size,
                              hipStream_t stream) {
    const float4* fake = (const float4*)d_in[0];
    const float4* real = (const float4*)d_in[1];
    float* out = (float*)d_out;
    double* partial = (double*)d_ws;   // needs NBLOCKS*5*8 = 153,600 B of scratch

    int total  = in_sizes[0];
    int total4 = total / 4;

    if (total4 == ITERS * THREADS_TOTAL) {
        ddd_reduce5_kernel<<<NBLOCKS, NTHREADS, 0, stream>>>(fake, real, partial);
    } else {
        ddd_reduce_gen_kernel<<<NBLOCKS, NTHREADS, 0, stream>>>(fake, real, partial, total4);
    }
    finalize_kernel<<<1, 1024, 0, stream>>>(partial, NBLOCKS, out);
}

// Round 7
// 36.016 us; speedup vs baseline: 6.9005x; 1.0339x over previous
//
#include <hip/hip_runtime.h>
#include <math.h>

#define NBLOCKS 1280
#define NTHREADS 256
#define THREADS_TOTAL (NBLOCKS * NTHREADS)   // 327,680
#define ITERS 15                              // 327,680 * 15 = 4,915,200 quads

// image geometry (fixed by the reference): W=640, H=480
#define ROW4 160
#define IMG4 76800

// constants from the reference
#define K_CX 313.0447587080473f
#define K_CY 238.44389626620386f
#define K_RFX (1.0f / 582.6244816773795f)
#define K_RFY (1.0f / 582.6910327098864f)
#define LN2_SQ 0.48045301391820142467f   // (ln 2)^2

// ---------------------------------------------------------------------------
// per-quad compute (col/row known): masked d^2*a^2, d^2*b^2, d^2, dlog^2, count
__device__ __forceinline__ void quad_accum(const float4& f, const float4& r,
                                           int col4, float b,
                                           float& sx, float& sy, float& sz,
                                           float& sl2, float& cnt) {
    float fv[4] = {f.x, f.y, f.z, f.w};
    float rv[4] = {r.x, r.y, r.z, r.w};
#pragma unroll
    for (int j = 0; j < 4; ++j) {
        float fj = fv[j], rj = rv[j];
        bool m = (rj > 0.f) & (rj < 1.f) & (fj > 0.f) & (fj < 1.f);
        // Inside the mask r,f in (0,1) and a,b != 0 (CX/CY non-integer) -> the
        // reference's ==0->eps replacements are no-ops; x/y diffs factor to d*a, d*b.
        float a  = ((float)(col4 + j) - K_CX) * K_RFX;
        float d  = rj - fj;
        float dl = __log2f(rj) - __log2f(fj);
        d  = m ? d  : 0.f;
        dl = m ? dl : 0.f;
        float da = d * a, db = d * b;
        sx  += da * da;
        sy  += db * db;
        sz  += d * d;
        sl2 += dl * dl;
        cnt += m ? 1.f : 0.f;
    }
}

// wave + block reduce, then store 5 partials for this block (SoA, no atomics)
__device__ __forceinline__ void block_reduce_store(
        float cnt, float sx, float sy, float sz, float sl,
        double* __restrict__ partial, int nb, int bid) {
#pragma unroll
    for (int o = 32; o > 0; o >>= 1) {
        cnt += __shfl_down(cnt, o);
        sx  += __shfl_down(sx, o);
        sy  += __shfl_down(sy, o);
        sz  += __shfl_down(sz, o);
        sl  += __shfl_down(sl, o);
    }
    __shared__ float part[4][5];
    int wave = threadIdx.x >> 6;
    int lane = threadIdx.x & 63;
    if (lane == 0) {
        part[wave][0] = cnt; part[wave][1] = sx; part[wave][2] = sy;
        part[wave][3] = sz;  part[wave][4] = sl;
    }
    __syncthreads();
    if (threadIdx.x == 0) {
        double t[5] = {0, 0, 0, 0, 0};
#pragma unroll
        for (int w = 0; w < 4; ++w)
#pragma unroll
            for (int j = 0; j < 5; ++j) t[j] += (double)part[w][j];
#pragma unroll
        for (int j = 0; j < 5; ++j) partial[j * nb + bid] = t[j];
    }
}

// ---------------------------------------------------------------------------
// fast path: exactly ITERS strided quads per thread; 1280 blocks -> single
// co-resident block-wave (5 blocks/CU, 20 waves/CU), no straggler wave.
__global__ __launch_bounds__(NTHREADS) void ddd_reduce15_kernel(
        const float4* __restrict__ fake, const float4* __restrict__ real,
        double* __restrict__ partial) {
    const int tid = blockIdx.x * NTHREADS + threadIdx.x;

    float cnt = 0.f, sx = 0.f, sy = 0.f, sz = 0.f, sl2 = 0.f;

    // two-phase per chunk: issue loads, then compute (compiler pipelines)
    float4 fb[ITERS], rb[ITERS];
#pragma unroll
    for (int k = 0; k < ITERS; ++k) {
        fb[k] = fake[tid + k * THREADS_TOTAL];
        rb[k] = real[tid + k * THREADS_TOTAL];
    }

#pragma unroll
    for (int k = 0; k < ITERS; ++k) {
        int idx  = tid + k * THREADS_TOTAL;
        int pos  = idx % IMG4;               // constant-divisor -> magic mul
        int col4 = (pos % ROW4) * 4;
        int h    = pos / ROW4;
        float b  = ((float)h - K_CY) * K_RFY;
        quad_accum(fb[k], rb[k], col4, b, sx, sy, sz, sl2, cnt);
    }

    block_reduce_store(cnt, sx, sy, sz, sl2 * LN2_SQ, partial, NBLOCKS, blockIdx.x);
}

// generic fallback: any total4 (grid-stride)
__global__ __launch_bounds__(NTHREADS) void ddd_reduce_gen_kernel(
        const float4* __restrict__ fake, const float4* __restrict__ real,
        double* __restrict__ partial, int total4) {
    float cnt = 0.f, sx = 0.f, sy = 0.f, sz = 0.f, sl2 = 0.f;
    for (int i = blockIdx.x * NTHREADS + threadIdx.x; i < total4; i += THREADS_TOTAL) {
        float4 f = fake[i];
        float4 r = real[i];
        int pos  = i % IMG4;
        int col4 = (pos % ROW4) * 4;
        int h    = pos / ROW4;
        float b  = ((float)h - K_CY) * K_RFY;
        quad_accum(f, r, col4, b, sx, sy, sz, sl2, cnt);
    }
    block_reduce_store(cnt, sx, sy, sz, sl2 * LN2_SQ, partial, NBLOCKS, blockIdx.x);
}

// ---------------------------------------------------------------------------
// finalize: 256 threads sum nb partials per quantity (nb*5*8 = 51 KB read)
__global__ __launch_bounds__(NTHREADS) void finalize_kernel(
        const double* __restrict__ partial, int nb, float* __restrict__ out) {
    double t[5] = {0, 0, 0, 0, 0};
    for (int i = threadIdx.x; i < nb; i += NTHREADS)
#pragma unroll
        for (int j = 0; j < 5; ++j) t[j] += partial[j * nb + i];
#pragma unroll
    for (int o = 32; o > 0; o >>= 1)
#pragma unroll
        for (int j = 0; j < 5; ++j) t[j] += __shfl_down(t[j], o);

    __shared__ double part[4][5];
    int wave = threadIdx.x >> 6;
    int lane = threadIdx.x & 63;
    if (lane == 0)
#pragma unroll
        for (int j = 0; j < 5; ++j) part[wave][j] = t[j];
    __syncthreads();

    if (threadIdx.x == 0) {
#pragma unroll
        for (int w = 1; w < 4; ++w)
#pragma unroll
            for (int j = 0; j < 5; ++j) part[0][j] += part[w][j];
        double n  = part[0][0];
        double lx = sqrt(part[0][1] / n);
        double ly = sqrt(part[0][2] / n);
        double lz = sqrt(part[0][3] / n);
        double ll = sqrt(part[0][4] / n);
        double loss = 10.0 * (ll + fabs(10.0 * (3.0 - exp(lx) - exp(ly) - exp(lz))));
        out[0] = (float)loss;
    }
}

// ---------------------------------------------------------------------------
extern "C" void kernel_launch(void* const* d_in, const int* in_sizes, int n_in,
                              void* d_out, int out_size, void* d_ws, size_t ws_size,
                              hipStream_t stream) {
    const float4* fake = (const float4*)d_in[0];
    const float4* real = (const float4*)d_in[1];
    float* out = (float*)d_out;
    double* partial = (double*)d_ws;   // needs NBLOCKS*5*8 = 51,200 B of scratch

    int total  = in_sizes[0];
    int total4 = total / 4;

    if (total4 == ITERS * THREADS_TOTAL) {
        ddd_reduce15_kernel<<<NBLOCKS, NTHREADS, 0, stream>>>(fake, real, partial);
    } else {
        ddd_reduce_gen_kernel<<<NBLOCKS, NTHREADS, 0, stream>>>(fake, real, partial, total4);
    }
    finalize_kernel<<<1, NTHREADS, 0, stream>>>(partial, NBLOCKS, out);
}